// Round 5
// baseline (279.206 us; speedup 1.0000x reference)
//
#include <hip/hip_runtime.h>
#include <hip/hip_bf16.h>
#include <math.h>

// Problem constants
#define BATCH 1024
#define NREAL 784
#define NPAD  896      // 7*128, zero-padded graph dim
#define C1D   32
#define C2D   32
#define HDIM  512
#define NCLS  10
#define KFC   25088    // 784*32

#define KS_G1 7        // split-K for G1 (K=896 -> 128/slice, 4 iters, EVEN)
#define KS_FC 14       // split-K for fc1 (K=25088 -> 1792/slice, 56 iters, EVEN)

// GEMM tile (128x128 kernel, used for G1/G4)
#define BM 128
#define BN 128
#define BK 32

using bf16x8  = __attribute__((ext_vector_type(8))) __bf16;
using floatx4 = __attribute__((ext_vector_type(4))) float;

__device__ __forceinline__ float elu_f(float t) {
    return t > 0.f ? t : (__expf(t) - 1.f);
}

// LDS-only barrier: waits ds ops but leaves global loads (vmcnt) in flight.
__device__ __forceinline__ void wg_barrier_lds() {
    asm volatile("s_waitcnt lgkmcnt(0)\n\ts_barrier" ::: "memory");
}

// raw barrier (no waitcnt)
__device__ __forceinline__ void bar() {
    asm volatile("s_barrier" ::: "memory");
}

// lgkm drain + scheduler fence (rule #18 / m201 template)
__device__ __forceinline__ void lgkm0_fence() {
    asm volatile("s_waitcnt lgkmcnt(0)" ::: "memory");
    __builtin_amdgcn_sched_barrier(0);
}

// async global->LDS, 16B per lane; LDS dest is wave-uniform base + lane*16
__device__ __forceinline__ void gload_lds16(const __hip_bfloat16* g, __hip_bfloat16* l) {
    __builtin_amdgcn_global_load_lds(
        (const __attribute__((address_space(1))) void*)g,
        (__attribute__((address_space(3))) void*)l, 16, 0, 0);
}

// ---------------------------------------------------------------------------
// BT-GEMM, register-staged pipeline + XOR-swizzled LDS layout (G1, G4).
// (unchanged)
// ---------------------------------------------------------------------------
template<int MODE>
__launch_bounds__(256)
__global__ void gemm_bt(const __hip_bfloat16* __restrict__ A, int lda,
                        const __hip_bfloat16* __restrict__ Bm, int ldb,
                        int kIters, int kPerZ, size_t sliceStride,
                        float* __restrict__ outF, int ldc,
                        __hip_bfloat16* __restrict__ outH,
                        const float* __restrict__ bias)
{
    __shared__ __align__(16) __hip_bfloat16 As[2][BM * BK];
    __shared__ __align__(16) __hip_bfloat16 Bs[2][BN * BK];

    const int tid  = threadIdx.x;
    const int lane = tid & 63;
    const int wave = tid >> 6;
    const int wi = wave >> 1, wj = wave & 1;

    const int m0 = blockIdx.y * BM;
    const int n0 = blockIdx.x * BN;
    const int kBase = blockIdx.z * kPerZ;

    const int rowInChunk = lane >> 2;
    const int kOff8 = (lane & 3) * 8;

    const __hip_bfloat16* aSrc0 = A  + (size_t)(m0 + (wave * 2 + 0) * 16 + rowInChunk) * lda + kBase + kOff8;
    const __hip_bfloat16* aSrc1 = A  + (size_t)(m0 + (wave * 2 + 1) * 16 + rowInChunk) * lda + kBase + kOff8;
    const __hip_bfloat16* bSrc0 = Bm + (size_t)(n0 + (wave * 2 + 0) * 16 + rowInChunk) * ldb + kBase + kOff8;
    const __hip_bfloat16* bSrc1 = Bm + (size_t)(n0 + (wave * 2 + 1) * 16 + rowInChunk) * ldb + kBase + kOff8;

    const int wSlot = (((lane & 3) + ((lane >> 3) & 3)) & 3) * 8;
    const int ldsW0 = (wave * 2 + 0) * 512 + rowInChunk * 32 + wSlot;
    const int ldsW1 = ldsW0 + 512;

    const int rSlot = ((((lane >> 4) + (((lane & 15) >> 1) & 3)) & 3)) * 8;
    const int rRow  = lane & 15;

    floatx4 acc[4][4];
    const floatx4 zero4 = {0.f, 0.f, 0.f, 0.f};
    #pragma unroll
    for (int i = 0; i < 4; i++)
        #pragma unroll
        for (int j = 0; j < 4; j++) acc[i][j] = zero4;

    int4 aA0, aA1, bA0, bA1;
    int4 aB0, aB1, bB0, bB1;

    aA0 = *(const int4*)aSrc0; aA1 = *(const int4*)aSrc1;
    bA0 = *(const int4*)bSrc0; bA1 = *(const int4*)bSrc1;
    aSrc0 += BK; aSrc1 += BK; bSrc0 += BK; bSrc1 += BK;
    aB0 = *(const int4*)aSrc0; aB1 = *(const int4*)aSrc1;
    bB0 = *(const int4*)bSrc0; bB1 = *(const int4*)bSrc1;
    aSrc0 += BK; aSrc1 += BK; bSrc0 += BK; bSrc1 += BK;

    *(int4*)(&As[0][ldsW0]) = aA0;
    *(int4*)(&As[0][ldsW1]) = aA1;
    *(int4*)(&Bs[0][ldsW0]) = bA0;
    *(int4*)(&Bs[0][ldsW1]) = bA1;
    wg_barrier_lds();

    for (int kt = 0; kt < kIters; kt += 2) {
        const bool more = (kt + 2 < kIters);

        {
            bf16x8 af[4], bfr[4];
            #pragma unroll
            for (int mi = 0; mi < 4; mi++)
                af[mi] = *(const bf16x8*)(&As[0][(wi * 64 + mi * 16 + rRow) * BK + rSlot]);
            #pragma unroll
            for (int nj = 0; nj < 4; nj++)
                bfr[nj] = *(const bf16x8*)(&Bs[0][(wj * 64 + nj * 16 + rRow) * BK + rSlot]);

            if (more) {
                aA0 = *(const int4*)aSrc0; aA1 = *(const int4*)aSrc1;
                bA0 = *(const int4*)bSrc0; bA1 = *(const int4*)bSrc1;
                aSrc0 += BK; aSrc1 += BK; bSrc0 += BK; bSrc1 += BK;
            }
            *(int4*)(&As[1][ldsW0]) = aB0;
            *(int4*)(&As[1][ldsW1]) = aB1;
            *(int4*)(&Bs[1][ldsW0]) = bB0;
            *(int4*)(&Bs[1][ldsW1]) = bB1;

            #pragma unroll
            for (int mi = 0; mi < 4; mi++)
                #pragma unroll
                for (int nj = 0; nj < 4; nj++)
                    acc[mi][nj] = __builtin_amdgcn_mfma_f32_16x16x32_bf16(af[mi], bfr[nj], acc[mi][nj], 0, 0, 0);

            wg_barrier_lds();
        }

        {
            bf16x8 af[4], bfr[4];
            #pragma unroll
            for (int mi = 0; mi < 4; mi++)
                af[mi] = *(const bf16x8*)(&As[1][(wi * 64 + mi * 16 + rRow) * BK + rSlot]);
            #pragma unroll
            for (int nj = 0; nj < 4; nj++)
                bfr[nj] = *(const bf16x8*)(&Bs[1][(wj * 64 + nj * 16 + rRow) * BK + rSlot]);

            if (more) {
                aB0 = *(const int4*)aSrc0; aB1 = *(const int4*)aSrc1;
                bB0 = *(const int4*)bSrc0; bB1 = *(const int4*)bSrc1;
                aSrc0 += BK; aSrc1 += BK; bSrc0 += BK; bSrc1 += BK;
                *(int4*)(&As[0][ldsW0]) = aA0;
                *(int4*)(&As[0][ldsW1]) = aA1;
                *(int4*)(&Bs[0][ldsW0]) = bA0;
                *(int4*)(&Bs[0][ldsW1]) = bA1;
            }

            #pragma unroll
            for (int mi = 0; mi < 4; mi++)
                #pragma unroll
                for (int nj = 0; nj < 4; nj++)
                    acc[mi][nj] = __builtin_amdgcn_mfma_f32_16x16x32_bf16(af[mi], bfr[nj], acc[mi][nj], 0, 0, 0);

            wg_barrier_lds();
        }
    }

    #pragma unroll
    for (int mi = 0; mi < 4; mi++) {
        #pragma unroll
        for (int nj = 0; nj < 4; nj++) {
            #pragma unroll
            for (int r = 0; r < 4; r++) {
                const int row = m0 + wi * 64 + mi * 16 + (lane >> 4) * 4 + r;
                const int col = n0 + wj * 64 + nj * 16 + (lane & 15);
                const float v = acc[mi][nj][r];
                if (MODE == 1) {
                    if (row < NREAL) {
                        const int c = col & 31, b = col >> 5;
                        const float t = elu_f(v + bias[c]);
                        outH[(size_t)b * KFC + row * 32 + c] = __float2bfloat16(t);
                    }
                } else {
                    outF[(size_t)blockIdx.z * sliceStride + (size_t)row * ldc + col] = v;
                }
            }
        }
    }
}

// ---------------------------------------------------------------------------
// G3: 256x256 quadrant-per-phase GEMM, half-slot ring + frag reuse +
//     m201-style per-phase barrier-pair discipline (T3+T4).
//
//   C[n][j] = sum_m Abf[n][m] * Tt[j][m].  K = 896 = 14 tiles of BK=64.
//
// Per phase (all 8 waves, lockstep): {ds_reads; [stage issues]; bar;
// lgkmcnt(0)+sched_barrier; setprio(1); 16 MFMA; setprio(0); bar}.
// Phase order (0,0),(0,1),(1,1),(1,0) with aF/bF register reuse: 28
// ds_read_b128/tile/wave.  The barrier pairs keep waves within one phase:
// next phase's LDS reads issue while the MFMA pipe drains (T3 mechanism).
//
// LDS: ring of 4 half-slots/matrix, slot(t,h)=(2t+h)&3 (128 KiB).
// Rotation swizzle in rows; staging = linear LDS dest + pre-swizzled
// global source (rule #21).
//
// Ledger:
//   issue:  t.P1: {A1,B0}(t+1)  [slots of A1,B0(t-1), retired by (t-1).P3/P4
//                                lgkm + post-MFMA barriers]
//           t.P3: {A0,B1}(t+2)  [slots of A0(t) (last read t.P1), B1(t)
//                                (last read t.P2) — behind P1/P2 barriers]
//   wait:   ONE vmcnt per tile, at t.P4 before the pre-MFMA barrier:
//           t+2<KT: vmcnt(4)  (youngest 4 = {A0,B1}(t+2); forces t+1's 8)
//           t==KT-2: vmcnt(0) (12.P3 skipped; drain {A1,B0}(13))
//           t==KT-1: none (nothing outstanding).
//           The P4 barrier pair then fences visibility for (t+1).P1 reads.
//   leads:  {A1,B0}(t+1): 3 phases; {A0,B1}(t+1): 5 phases.
// ---------------------------------------------------------------------------
#define KT_G3 14

#define STAGE_A(tt, hh) do {                                                    \
    const int s_ = (2 * (tt) + (hh)) & 3;                                       \
    gload_lds16(aSrcH[hh][0] + (tt) * 64, &Ah[s_][(wave * 2 + 0) * 512]);       \
    gload_lds16(aSrcH[hh][1] + (tt) * 64, &Ah[s_][(wave * 2 + 1) * 512]);       \
} while (0)

#define STAGE_B(tt, hh) do {                                                    \
    const int s_ = (2 * (tt) + (hh)) & 3;                                       \
    gload_lds16(bSrcH[hh][0] + (tt) * 64, &Bh[s_][(wave * 2 + 0) * 512]);       \
    gload_lds16(bSrcH[hh][1] + (tt) * 64, &Bh[s_][(wave * 2 + 1) * 512]);       \
} while (0)

#define MFMA_CLUSTER(Q)                                                         \
    lgkm0_fence();                                                              \
    __builtin_amdgcn_s_setprio(1);                                              \
    _Pragma("unroll")                                                           \
    for (int mi_ = 0; mi_ < 4; mi_++)                                           \
        _Pragma("unroll")                                                       \
        for (int nj_ = 0; nj_ < 2; nj_++)                                       \
            acc[Q][mi_][nj_] = __builtin_amdgcn_mfma_f32_16x16x32_bf16(         \
                aF[mi_][0], bF[nj_][0], acc[Q][mi_][nj_], 0, 0, 0);             \
    _Pragma("unroll")                                                           \
    for (int mi_ = 0; mi_ < 4; mi_++)                                           \
        _Pragma("unroll")                                                       \
        for (int nj_ = 0; nj_ < 2; nj_++)                                       \
            acc[Q][mi_][nj_] = __builtin_amdgcn_mfma_f32_16x16x32_bf16(         \
                aF[mi_][1], bF[nj_][1], acc[Q][mi_][nj_], 0, 0, 0);             \
    __builtin_amdgcn_s_setprio(0);                                              \
    bar();

__launch_bounds__(512, 2)
__global__ void gemm256_g3(const __hip_bfloat16* __restrict__ Ag,   // Abf [896][896]
                           const __hip_bfloat16* __restrict__ Bg,   // Tt  [32768][896]
                           __hip_bfloat16* __restrict__ outH,       // h2f
                           const float* __restrict__ bias)          // b2 [32]
{
    __shared__ __align__(16) __hip_bfloat16 Ah[4][128 * 64];
    __shared__ __align__(16) __hip_bfloat16 Bh[4][128 * 64];

    const int tid  = threadIdx.x;
    const int lane = tid & 63;
    const int wave = tid >> 6;
    const int vm = wave >> 2, vn = wave & 3;

    const int mR = blockIdx.y * 256;    // output rows (Abf rows; >=896 clamped+masked)
    const int nR = blockIdx.x * 256;    // output cols (Tt rows)

    // ---- read-side constants ----
    const int rRow = lane & 15;
    const int gHi  = lane >> 4;              // 0..3 (k-group within half-K)
    const int rot  = lane & 7;               // == (read row) & 7
    const int koff0 = (((gHi + rot) & 7) << 3);
    const int koff1 = ((((gHi + 4) + rot) & 7) << 3);
    const int aBase = (vm * 64 + rRow) * 64;   // + mi*1024, within a 128-row A-half
    const int bBase = (vn * 32 + rRow) * 64;   // + nj*1024, within a 128-row B-half

    // ---- staging constants (pre-swizzled global source, linear LDS dest) ----
    const int rowLoc = lane >> 3;                       // row within 8-row chunk
    const int gOff   = ((((lane & 7) - rowLoc) & 7) << 3);
    const __hip_bfloat16* aSrcH[2][2];
    const __hip_bfloat16* bSrcH[2][2];
    #pragma unroll
    for (int h = 0; h < 2; h++)
        #pragma unroll
        for (int j = 0; j < 2; j++) {
            int ra = mR + h * 128 + (wave * 2 + j) * 8 + rowLoc;
            if (ra > NPAD - 1) ra = NPAD - 1;   // clamp: garbage rows store-masked
            aSrcH[h][j] = Ag + (size_t)ra * NPAD + gOff;
            const int rb = nR + h * 128 + (wave * 2 + j) * 8 + rowLoc;
            bSrcH[h][j] = Bg + (size_t)rb * NPAD + gOff;
        }

    // per-thread bias values (col&31 = nj*16 + rRow)
    const float bias0 = bias[rRow];
    const float bias1 = bias[16 + rRow];

    floatx4 acc[4][4][2];      // [QM*2+QN][mi][nj]
    const floatx4 zero4 = {0.f, 0.f, 0.f, 0.f};
    #pragma unroll
    for (int q = 0; q < 4; q++)
        #pragma unroll
        for (int i = 0; i < 4; i++)
            #pragma unroll
            for (int j = 0; j < 2; j++) acc[q][i][j] = zero4;

    // ---- prologue: {A0,B1}(0), {A1,B0}(0), {A0,B1}(1); wait tile-0 ----
    STAGE_A(0, 0); STAGE_B(0, 1);
    STAGE_A(0, 1); STAGE_B(0, 0);
    STAGE_A(1, 0); STAGE_B(1, 1);
    asm volatile("s_waitcnt vmcnt(4)" ::: "memory");
    bar();

    #pragma unroll 2
    for (int t = 0; t < KT_G3; ++t) {
        const int sA0 = (2 * t + 0) & 3, sA1 = (2 * t + 1) & 3;
        const int sB0 = (2 * t + 0) & 3, sB1 = (2 * t + 1) & 3;

        bf16x8 aF[4][2], bF[2][2];

        // ---- P1: quadrant (0,0) — read aF<-A0, bF<-B0; stage {A1,B0}(t+1) ----
        #pragma unroll
        for (int mi = 0; mi < 4; mi++) {
            aF[mi][0] = *(const bf16x8*)(&Ah[sA0][aBase + mi * 1024 + koff0]);
            aF[mi][1] = *(const bf16x8*)(&Ah[sA0][aBase + mi * 1024 + koff1]);
        }
        #pragma unroll
        for (int nj = 0; nj < 2; nj++) {
            bF[nj][0] = *(const bf16x8*)(&Bh[sB0][bBase + nj * 1024 + koff0]);
            bF[nj][1] = *(const bf16x8*)(&Bh[sB0][bBase + nj * 1024 + koff1]);
        }
        if (t + 1 < KT_G3) { STAGE_A(t + 1, 1); STAGE_B(t + 1, 0); }
        bar();
        MFMA_CLUSTER(0)

        // ---- P2: quadrant (0,1) — reuse aF(A0), read bF<-B1 ----
        #pragma unroll
        for (int nj = 0; nj < 2; nj++) {
            bF[nj][0] = *(const bf16x8*)(&Bh[sB1][bBase + nj * 1024 + koff0]);
            bF[nj][1] = *(const bf16x8*)(&Bh[sB1][bBase + nj * 1024 + koff1]);
        }
        bar();
        MFMA_CLUSTER(1)

        // ---- P3: quadrant (1,1) — read aF<-A1, reuse bF(B1); stage {A0,B1}(t+2) ----
        #pragma unroll
        for (int mi = 0; mi < 4; mi++) {
            aF[mi][0] = *(const bf16x8*)(&Ah[sA1][aBase + mi * 1024 + koff0]);
            aF[mi][1] = *(const bf16x8*)(&Ah[sA1][aBase + mi * 1024 + koff1]);
        }
        if (t + 2 < KT_G3) { STAGE_A(t + 2, 0); STAGE_B(t + 2, 1); }
        bar();
        MFMA_CLUSTER(3)

        // ---- P4: quadrant (1,0) — reuse aF(A1), read bF<-B0; counted vmcnt ----
        #pragma unroll
        for (int nj = 0; nj < 2; nj++) {
            bF[nj][0] = *(const bf16x8*)(&Bh[sB0][bBase + nj * 1024 + koff0]);
            bF[nj][1] = *(const bf16x8*)(&Bh[sB0][bBase + nj * 1024 + koff1]);
        }
        if (t + 2 < KT_G3)      { asm volatile("s_waitcnt vmcnt(4)" ::: "memory"); }
        else if (t + 1 < KT_G3) { asm volatile("s_waitcnt vmcnt(0)" ::: "memory"); }
        bar();
        MFMA_CLUSTER(2)
    }

    // ---- epilogue: C/D layout col=lane&15, row=(lane>>4)*4+reg (m89/m91) ----
    #pragma unroll
    for (int q = 0; q < 4; q++) {
        const int qm = q >> 1, qn = q & 1;
        #pragma unroll
        for (int mi = 0; mi < 4; mi++) {
            #pragma unroll
            for (int nj = 0; nj < 2; nj++) {
                #pragma unroll
                for (int r = 0; r < 4; r++) {
                    const int row = mR + qm * 128 + vm * 64 + mi * 16 + gHi * 4 + r;
                    if (row < NREAL) {
                        const int col = nR + qn * 128 + vn * 32 + nj * 16 + rRow;
                        const int c = col & 31, b = col >> 5;
                        const float bv = nj ? bias1 : bias0;
                        const float v = elu_f(acc[q][mi][nj][r] + bv);
                        outH[(size_t)b * KFC + row * 32 + c] = __float2bfloat16(v);
                    }
                }
            }
        }
    }
}

// ---------------------------------------------------------------------------
// Conversions / padding (convX + convA merged: one launch)
// ---------------------------------------------------------------------------
#define NBLK_X ((BATCH * NPAD + 255) / 256)
#define NBLK_A ((NPAD * NPAD + 255) / 256)

__global__ void convXA(const float* __restrict__ x, __hip_bfloat16* __restrict__ Xbf,
                       const float* __restrict__ a, __hip_bfloat16* __restrict__ Abf)
{
    if (blockIdx.x < NBLK_X) {
        const int idx = blockIdx.x * 256 + threadIdx.x;
        if (idx >= BATCH * NPAD) return;
        const int m = idx % NPAD, b = idx / NPAD;
        const float v = (m < NREAL) ? x[(size_t)b * NREAL + m] : 0.f;
        Xbf[idx] = __float2bfloat16(v);
    } else {
        const int idx = (blockIdx.x - NBLK_X) * 256 + threadIdx.x;
        if (idx >= NPAD * NPAD) return;
        const int m = idx % NPAD, n = idx / NPAD;
        const float v = (m < NREAL && n < NREAL) ? a[(size_t)n * NREAL + m] : 0.f;
        Abf[idx] = __float2bfloat16(v);
    }
}

// wf1 [25088][512] fp32 -> Wt [512][25088] bf16 (LDS tile transpose)
__global__ void convW(const float* __restrict__ wf1, __hip_bfloat16* __restrict__ Wt) {
    __shared__ float tile[32][33];
    const int k0 = blockIdx.x * 32, h0 = blockIdx.y * 32;
    const int tx = threadIdx.x, ty = threadIdx.y;  // (32,8)
    #pragma unroll
    for (int i = 0; i < 4; i++)
        tile[ty * 4 + i][tx] = wf1[(size_t)(k0 + ty * 4 + i) * HDIM + h0 + tx];
    __syncthreads();
    #pragma unroll
    for (int i = 0; i < 4; i++)
        Wt[(size_t)(h0 + ty * 4 + i) * KFC + k0 + tx] = __float2bfloat16(tile[tx][ty * 4 + i]);
}

// ---------------------------------------------------------------------------
// Layer-1 fused pointwise
// ---------------------------------------------------------------------------
__global__ void layer1_fuse(const float* __restrict__ Ypart,
                            const float* __restrict__ w1, const float* __restrict__ b1,
                            const float* __restrict__ w2,
                            __hip_bfloat16* __restrict__ Tt)
{
    __shared__ __align__(16) float sW2[C1D * C2D];
    __shared__ float sw1[C1D], sb1[C1D];
    const int tid = threadIdx.x;                 // 128 threads
    for (int i = tid; i < C1D * C2D; i += 128) sW2[i] = w2[i];
    if (tid < C1D) { sw1[tid] = w1[tid]; sb1[tid] = b1[tid]; }
    __syncthreads();

    const int m = blockIdx.x * 128 + tid;        // 0..895
    const int b = blockIdx.y;
    float y = 0.f;
    #pragma unroll
    for (int z = 0; z < KS_G1; z++)
        y += Ypart[(size_t)z * (BATCH * NPAD) + (size_t)b * NPAD + m];

    float h[C1D];
    #pragma unroll
    for (int c1 = 0; c1 < C1D; c1++) h[c1] = elu_f(y * sw1[c1] + sb1[c1]);

    float4 t4[8];
    #pragma unroll
    for (int q = 0; q < 8; q++) t4[q] = make_float4(0.f, 0.f, 0.f, 0.f);
    #pragma unroll
    for (int c1 = 0; c1 < C1D; c1++) {
        const float hv = h[c1];
        const float4* row = (const float4*)(sW2 + c1 * C2D);
        #pragma unroll
        for (int q = 0; q < 8; q++) {
            const float4 w = row[q];
            t4[q].x += hv * w.x; t4[q].y += hv * w.y;
            t4[q].z += hv * w.z; t4[q].w += hv * w.w;
        }
    }
    const float* tf = (const float*)t4;
    #pragma unroll
    for (int c = 0; c < C2D; c++)
        Tt[((size_t)(b * 32 + c)) * NPAD + m] = __float2bfloat16(tf[c]);
}

// ---------------------------------------------------------------------------
// fc1 reduce + relu + fc2 + softmax, fused.
// ---------------------------------------------------------------------------
__global__ void fc2_softmax(const float* __restrict__ part, const float* __restrict__ bf1,
                            const float* __restrict__ wf2, const float* __restrict__ bf2,
                            float* __restrict__ out)
{
    __shared__ float sW[HDIM * NCLS];
    __shared__ float sb[NCLS];
    const int tid = threadIdx.x;                 // 256
    for (int i = tid; i < HDIM * NCLS; i += 256) sW[i] = wf2[i];
    if (tid < NCLS) sb[tid] = bf2[tid];
    __syncthreads();

    const int lane = tid & 63, wave = tid >> 6;
    const int b = blockIdx.x * 4 + wave;

    float acc[NCLS];
    #pragma unroll
    for (int c = 0; c < NCLS; c++) acc[c] = 0.f;
    #pragma unroll
    for (int q = 0; q < 8; q++) {
        const int h = q * 64 + lane;
        float hv = bf1[h];
        #pragma unroll
        for (int z = 0; z < KS_FC; z++)
            hv += part[(size_t)z * (BATCH * HDIM) + (size_t)b * HDIM + h];
        hv = hv > 0.f ? hv : 0.f;
        #pragma unroll
        for (int c = 0; c < NCLS; c++) acc[c] += hv * sW[h * NCLS + c];
    }
    #pragma unroll
    for (int c = 0; c < NCLS; c++) {
        #pragma unroll
        for (int off = 32; off >= 1; off >>= 1) acc[c] += __shfl_down(acc[c], off);
    }
    if (lane == 0) {
        float mx = -1e30f;
        #pragma unroll
        for (int c = 0; c < NCLS; c++) { acc[c] += sb[c]; mx = fmaxf(mx, acc[c]); }
        float e[NCLS], s = 0.f;
        #pragma unroll
        for (int c = 0; c < NCLS; c++) { e[c] = __expf(acc[c] - mx); s += e[c]; }
        const float inv = 1.f / s;
        #pragma unroll
        for (int c = 0; c < NCLS; c++) out[(size_t)b * NCLS + c] = e[c] * inv;
    }
}

// ---------------------------------------------------------------------------
// Workspace layout (peak ~113.5 MB) — unchanged
//   h2f   [0,          51380224)  bf16 1024x25088  (written G3, read G4)
//     Ypart [0, 25690112) f32 7x1024x896 — overlay, dead before G3 writes h2f
//   Tt    [51380224,  110100480)  bf16 32768x896   (dead after G3)
//     Wt   [51380224, 77070336)   bf16 512x25088 — overlay after G3
//     part [77070336, 106430464)  f32 14x1024x512 — overlay after G3
//   Abf   [110100480, 111706112)  bf16 896x896
//   Xbf   [111706112, 113541120)  bf16 1024x896    (dead after G1)
// ---------------------------------------------------------------------------
extern "C" void kernel_launch(void* const* d_in, const int* in_sizes, int n_in,
                              void* d_out, int out_size, void* d_ws, size_t ws_size,
                              hipStream_t stream)
{
    const float* x   = (const float*)d_in[0];
    const float* a   = (const float*)d_in[1];
    const float* w1  = (const float*)d_in[2];
    const float* b1  = (const float*)d_in[3];
    const float* w2  = (const float*)d_in[4];
    const float* b2  = (const float*)d_in[5];
    const float* wf1 = (const float*)d_in[6];
    const float* bf1 = (const float*)d_in[7];
    const float* wf2 = (const float*)d_in[8];
    const float* bf2 = (const float*)d_in[9];
    float* out = (float*)d_out;

    char* ws = (char*)d_ws;
    __hip_bfloat16* h2f  = (__hip_bfloat16*)(ws + 0);
    float*          Ypart= (float*)(ws + 0);                  // overlay (pre-G3)
    __hip_bfloat16* Tt   = (__hip_bfloat16*)(ws + 51380224);
    __hip_bfloat16* Wt   = (__hip_bfloat16*)(ws + 51380224);  // overlay (post-G3)
    float*          part = (float*)(ws + 77070336);           // overlay (post-G3)
    __hip_bfloat16* Abf  = (__hip_bfloat16*)(ws + 110100480);
    __hip_bfloat16* Xbf  = (__hip_bfloat16*)(ws + 111706112);

    // fused input conversions (one launch)
    convXA<<<NBLK_X + NBLK_A, 256, 0, stream>>>(x, Xbf, a, Abf);

    // G1: Ypart[z][b][n] partials of sum_m Xbf[b][m]*Abf[n][m]
    gemm_bt<2><<<dim3(NPAD / BN, BATCH / BM, KS_G1), 256, 0, stream>>>(
        Xbf, NPAD, Abf, NPAD, (NPAD / KS_G1) / BK, NPAD / KS_G1,
        (size_t)BATCH * NPAD, Ypart, NPAD, nullptr, nullptr);

    // layer-1 pointwise + @W2, transposed store
    layer1_fuse<<<dim3(NPAD / 128, BATCH), 128, 0, stream>>>(Ypart, w1, b1, w2, Tt);

    // G3: h2 = elu(A @ T + b2) — quadrant-phase + barrier-pair 256^2 kernel
    gemm256_g3<<<dim3(BATCH * 32 / 256, 1024 / 256), 512, 0, stream>>>(Abf, Tt, h2f, b2);

    // transpose wf1 -> bf16 (into the now-dead Tt region)
    convW<<<dim3(KFC / 32, HDIM / 32), dim3(32, 8), 0, stream>>>(wf1, Wt);

    // G4: fc1 partials, split-K=14
    gemm_bt<2><<<dim3(HDIM / BN, BATCH / BM, KS_FC), 256, 0, stream>>>(
        h2f, KFC, Wt, KFC, (KFC / KS_FC) / BK, KFC / KS_FC,
        (size_t)BATCH * HDIM, part, HDIM, nullptr, nullptr);

    // fc1 reduce + relu + fc2 + softmax
    fc2_softmax<<<BATCH / 4, 256, 0, stream>>>(part, bf1, wf2, bf2, out);
}

// Round 6
// 265.097 us; speedup vs baseline: 1.0532x; 1.0532x over previous
//
#include <hip/hip_runtime.h>
#include <hip/hip_bf16.h>
#include <math.h>

// Problem constants
#define BATCH 1024
#define NREAL 784
#define NPAD  896      // 7*128, zero-padded graph dim
#define C1D   32
#define C2D   32
#define HDIM  512
#define NCLS  10
#define KFC   25088    // 784*32

#define KS_G1 7        // split-K for G1 (K=896 -> 128/slice, 2 tiles of 64)
#define KS_FC 14       // split-K for fc1 (K=25088 -> 1792/slice, 28 tiles of 64)

using bf16x8  = __attribute__((ext_vector_type(8))) __bf16;
using floatx4 = __attribute__((ext_vector_type(4))) float;

__device__ __forceinline__ float elu_f(float t) {
    return t > 0.f ? t : (__expf(t) - 1.f);
}

// raw barrier (no waitcnt)
__device__ __forceinline__ void bar() {
    asm volatile("s_barrier" ::: "memory");
}

// async global->LDS, 16B per lane; LDS dest is wave-uniform base + lane*16
__device__ __forceinline__ void gload_lds16(const __hip_bfloat16* g, __hip_bfloat16* l) {
    __builtin_amdgcn_global_load_lds(
        (const __attribute__((address_space(1))) void*)g,
        (__attribute__((address_space(3))) void*)l, 16, 0, 0);
}

// ---------------------------------------------------------------------------
// gemm128_rg: 128x128 split-K BT-GEMM with half-slot ring (G1, G4).
//
//   out[z][row][col] = sum_{k in slice z} A[row][k] * Bm[col][k]   (fp32)
//
// 4 waves (vm=w>>1, vn=w&1); wave OWNS 64x64: reads A-half vm, B-half vn
// (amp 2x each).  BK=64, kTiles = kPerZ/64.  LDS: 4 half-slots/matrix,
// slot(t,h) = (2t+h)&3, half = 64x64 bf16 = 8KB -> 64 KiB total ->
// 2 blocks/CU (the co-resident block hides boundary stalls).
//
// Rotation swizzle within rows (slot(k>>3) = (k>>3 + row&7)&7): reads
// 2-way-free; staging = linear LDS dest + pre-swizzled global src (#21).
//
// Schedule per tile (ONE barrier + ONE vmcnt):
//   {vmcnt(0); bar; 16 ds_read_b128; stage tile t+1 (8 gloads); 32 MFMA}
// Ledger: stage(t+1) slots = (2t+2+h)&3 = slots(t-1) — disjoint from
// slots(t) = {2t&3,(2t+1)&3}; t-1's reads are behind the boundary bar ->
// WAR safe.  RAW: tile-t loads issued during t-1 (~full tile lead),
// drained by boundary vmcnt(0)+bar.
// ---------------------------------------------------------------------------
#define STAGE128_A(tt, hh) do {                                                 \
    const int s_ = (2 * (tt) + (hh)) & 3;                                       \
    gload_lds16(aSrcH[hh][0] + (tt) * 64, &Ah[s_][(wave * 2 + 0) * 512]);       \
    gload_lds16(aSrcH[hh][1] + (tt) * 64, &Ah[s_][(wave * 2 + 1) * 512]);       \
} while (0)

#define STAGE128_B(tt, hh) do {                                                 \
    const int s_ = (2 * (tt) + (hh)) & 3;                                       \
    gload_lds16(bSrcH[hh][0] + (tt) * 64, &Bh[s_][(wave * 2 + 0) * 512]);       \
    gload_lds16(bSrcH[hh][1] + (tt) * 64, &Bh[s_][(wave * 2 + 1) * 512]);       \
} while (0)

__launch_bounds__(256, 2)
__global__ void gemm128_rg(const __hip_bfloat16* __restrict__ A, int lda,
                           const __hip_bfloat16* __restrict__ Bm, int ldb,
                           int kTiles, int kPerZ, size_t sliceStride,
                           float* __restrict__ outF, int ldc)
{
    __shared__ __align__(16) __hip_bfloat16 Ah[4][64 * 64];
    __shared__ __align__(16) __hip_bfloat16 Bh[4][64 * 64];

    const int tid  = threadIdx.x;
    const int lane = tid & 63;
    const int wave = tid >> 6;          // 0..3
    const int vm = wave >> 1, vn = wave & 1;

    const int m0 = blockIdx.y * 128;
    const int n0 = blockIdx.x * 128;
    const int kBase = blockIdx.z * kPerZ;

    // ---- read-side constants (verified swizzle math, carried from G3) ----
    const int rRow = lane & 15;
    const int gHi  = lane >> 4;
    const int rot  = lane & 7;               // == (read row) & 7
    const int koff0 = (((gHi + rot) & 7) << 3);
    const int koff1 = ((((gHi + 4) + rot) & 7) << 3);

    // ---- staging constants (pre-swizzled global src, linear LDS dest) ----
    const int rowLoc = lane >> 3;
    const int gOff   = ((((lane & 7) - rowLoc) & 7) << 3);
    const __hip_bfloat16* aSrcH[2][2];
    const __hip_bfloat16* bSrcH[2][2];
    #pragma unroll
    for (int h = 0; h < 2; h++)
        #pragma unroll
        for (int j = 0; j < 2; j++) {
            const int ra = m0 + h * 64 + (wave * 2 + j) * 8 + rowLoc;
            aSrcH[h][j] = A  + (size_t)ra * lda + kBase + gOff;
            const int rb = n0 + h * 64 + (wave * 2 + j) * 8 + rowLoc;
            bSrcH[h][j] = Bm + (size_t)rb * ldb + kBase + gOff;
        }

    floatx4 acc[4][4];
    const floatx4 zero4 = {0.f, 0.f, 0.f, 0.f};
    #pragma unroll
    for (int i = 0; i < 4; i++)
        #pragma unroll
        for (int j = 0; j < 4; j++) acc[i][j] = zero4;

    // ---- prologue: stage tile 0 (4 halves, 8 gloads/wave) ----
    STAGE128_A(0, 0); STAGE128_A(0, 1);
    STAGE128_B(0, 0); STAGE128_B(0, 1);

    #pragma unroll 2
    for (int t = 0; t < kTiles; ++t) {
        asm volatile("s_waitcnt vmcnt(0)" ::: "memory");
        bar();

        const int sA = (2 * t + vm) & 3;
        const int sB = (2 * t + vn) & 3;
        const __hip_bfloat16* Ab = &Ah[sA][rRow * 64];
        const __hip_bfloat16* Bb = &Bh[sB][rRow * 64];

        bf16x8 aF[4][2], bF[4][2];
        #pragma unroll
        for (int mi = 0; mi < 4; mi++) {
            aF[mi][0] = *(const bf16x8*)(Ab + mi * 1024 + koff0);
            aF[mi][1] = *(const bf16x8*)(Ab + mi * 1024 + koff1);
        }
        #pragma unroll
        for (int nj = 0; nj < 4; nj++) {
            bF[nj][0] = *(const bf16x8*)(Bb + nj * 1024 + koff0);
            bF[nj][1] = *(const bf16x8*)(Bb + nj * 1024 + koff1);
        }

        if (t + 1 < kTiles) {
            STAGE128_A(t + 1, 0); STAGE128_A(t + 1, 1);
            STAGE128_B(t + 1, 0); STAGE128_B(t + 1, 1);
        }

        __builtin_amdgcn_s_setprio(1);
        #pragma unroll
        for (int mi = 0; mi < 4; mi++)
            #pragma unroll
            for (int nj = 0; nj < 4; nj++)
                acc[mi][nj] = __builtin_amdgcn_mfma_f32_16x16x32_bf16(aF[mi][0], bF[nj][0], acc[mi][nj], 0, 0, 0);
        #pragma unroll
        for (int mi = 0; mi < 4; mi++)
            #pragma unroll
            for (int nj = 0; nj < 4; nj++)
                acc[mi][nj] = __builtin_amdgcn_mfma_f32_16x16x32_bf16(aF[mi][1], bF[nj][1], acc[mi][nj], 0, 0, 0);
        __builtin_amdgcn_s_setprio(0);
    }

    // ---- epilogue: C/D layout col=lane&15, row=(lane>>4)*4+reg (m89/m91) ----
    #pragma unroll
    for (int mi = 0; mi < 4; mi++) {
        #pragma unroll
        for (int nj = 0; nj < 4; nj++) {
            #pragma unroll
            for (int r = 0; r < 4; r++) {
                const int row = m0 + vm * 64 + mi * 16 + gHi * 4 + r;
                const int col = n0 + vn * 64 + nj * 16 + rRow;
                outF[(size_t)blockIdx.z * sliceStride + (size_t)row * ldc + col] = acc[mi][nj][r];
            }
        }
    }
}

// ---------------------------------------------------------------------------
// G3: 256x256 quadrant-per-phase GEMM, half-slot ring + frag reuse (R4
// structure — the measured best: 69.8 us, MfmaUtil 34%) + B0-register-cache
// (P4 reuses P1's B0 frags: 28 -> 24 ds_read_b128/tile/wave = the 2x4
// decomposition's LDS-read minimum, 192 KB/CU/tile).
//
// Ledger (unchanged from R4; B0's slot lifetime only SHRINKS):
//   issue:  t.P1: {A1,B0}(t+1)  [slots of A1,B0(t-1), behind boundary bar]
//           t.P3: {A0,B1}(t+2)  [slots of A0(t)/B1(t), read P1/P2, behind
//                                the mid bar]
//   wait:   boundary vmcnt(4) ({A0,B1}(t+1) stay in flight); t=13: vmcnt(0)
//   barriers: 2/tile (boundary, mid).  Loose within-tile (no lockstep —
//   R1/R5 both showed barrier-pair lockstep regresses at this geometry).
// ---------------------------------------------------------------------------
#define KT_G3 14

#define STAGE_A(tt, hh) do {                                                    \
    const int s_ = (2 * (tt) + (hh)) & 3;                                       \
    gload_lds16(aSrcH[hh][0] + (tt) * 64, &Ah[s_][(wave * 2 + 0) * 512]);       \
    gload_lds16(aSrcH[hh][1] + (tt) * 64, &Ah[s_][(wave * 2 + 1) * 512]);       \
} while (0)

#define STAGE_B(tt, hh) do {                                                    \
    const int s_ = (2 * (tt) + (hh)) & 3;                                       \
    gload_lds16(bSrcH[hh][0] + (tt) * 64, &Bh[s_][(wave * 2 + 0) * 512]);       \
    gload_lds16(bSrcH[hh][1] + (tt) * 64, &Bh[s_][(wave * 2 + 1) * 512]);       \
} while (0)

__launch_bounds__(512, 2)
__global__ void gemm256_g3(const __hip_bfloat16* __restrict__ Ag,   // Abf [896][896]
                           const __hip_bfloat16* __restrict__ Bg,   // Tt  [32768][896]
                           __hip_bfloat16* __restrict__ outH,       // h2f
                           const float* __restrict__ bias)          // b2 [32]
{
    __shared__ __align__(16) __hip_bfloat16 Ah[4][128 * 64];
    __shared__ __align__(16) __hip_bfloat16 Bh[4][128 * 64];

    const int tid  = threadIdx.x;
    const int lane = tid & 63;
    const int wave = tid >> 6;
    const int vm = wave >> 2, vn = wave & 3;

    const int mR = blockIdx.y * 256;    // output rows (Abf rows; >=896 clamped+masked)
    const int nR = blockIdx.x * 256;    // output cols (Tt rows)

    // ---- read-side constants ----
    const int rRow = lane & 15;
    const int gHi  = lane >> 4;              // 0..3 (k-group within half-K)
    const int rot  = lane & 7;               // == (read row) & 7
    const int koff0 = (((gHi + rot) & 7) << 3);
    const int koff1 = ((((gHi + 4) + rot) & 7) << 3);
    const int aBase = (vm * 64 + rRow) * 64;   // + mi*1024, within a 128-row A-half
    const int bBase = (vn * 32 + rRow) * 64;   // + nj*1024, within a 128-row B-half

    // ---- staging constants (pre-swizzled global source, linear LDS dest) ----
    const int rowLoc = lane >> 3;                       // row within 8-row chunk
    const int gOff   = ((((lane & 7) - rowLoc) & 7) << 3);
    const __hip_bfloat16* aSrcH[2][2];
    const __hip_bfloat16* bSrcH[2][2];
    #pragma unroll
    for (int h = 0; h < 2; h++)
        #pragma unroll
        for (int j = 0; j < 2; j++) {
            int ra = mR + h * 128 + (wave * 2 + j) * 8 + rowLoc;
            if (ra > NPAD - 1) ra = NPAD - 1;   // clamp: garbage rows store-masked
            aSrcH[h][j] = Ag + (size_t)ra * NPAD + gOff;
            const int rb = nR + h * 128 + (wave * 2 + j) * 8 + rowLoc;
            bSrcH[h][j] = Bg + (size_t)rb * NPAD + gOff;
        }

    // per-thread bias values (col&31 = nj*16 + rRow)
    const float bias0 = bias[rRow];
    const float bias1 = bias[16 + rRow];

    floatx4 acc[4][4][2];      // [QM*2+QN][mi][nj]
    const floatx4 zero4 = {0.f, 0.f, 0.f, 0.f};
    #pragma unroll
    for (int q = 0; q < 4; q++)
        #pragma unroll
        for (int i = 0; i < 4; i++)
            #pragma unroll
            for (int j = 0; j < 2; j++) acc[q][i][j] = zero4;

    // ---- prologue (ledger order): {A0,B1}(0), {A1,B0}(0), {A0,B1}(1) ----
    STAGE_A(0, 0); STAGE_B(0, 1);
    STAGE_A(0, 1); STAGE_B(0, 0);
    STAGE_A(1, 0); STAGE_B(1, 1);

    #pragma unroll 2
    for (int t = 0; t < KT_G3; ++t) {
        // boundary: single counted wait covers all 4 halves of tile t
        if (t + 1 < KT_G3) { asm volatile("s_waitcnt vmcnt(4)" ::: "memory"); }
        else               { asm volatile("s_waitcnt vmcnt(0)" ::: "memory"); }
        bar();

        const int sA0 = (2 * t + 0) & 3, sA1 = (2 * t + 1) & 3;
        const int sB0 = (2 * t + 0) & 3, sB1 = (2 * t + 1) & 3;

        bf16x8 aF[4][2], bF0[2][2], bF1[2][2];

        // ---- P1: quadrant (0,0) — read aF<-A0, bF0<-B0; stage {A1,B0}(t+1) ----
        #pragma unroll
        for (int mi = 0; mi < 4; mi++) {
            aF[mi][0] = *(const bf16x8*)(&Ah[sA0][aBase + mi * 1024 + koff0]);
            aF[mi][1] = *(const bf16x8*)(&Ah[sA0][aBase + mi * 1024 + koff1]);
        }
        #pragma unroll
        for (int nj = 0; nj < 2; nj++) {
            bF0[nj][0] = *(const bf16x8*)(&Bh[sB0][bBase + nj * 1024 + koff0]);
            bF0[nj][1] = *(const bf16x8*)(&Bh[sB0][bBase + nj * 1024 + koff1]);
        }
        if (t + 1 < KT_G3) { STAGE_A(t + 1, 1); STAGE_B(t + 1, 0); }
        __builtin_amdgcn_s_setprio(1);
        #pragma unroll
        for (int mi = 0; mi < 4; mi++)
            #pragma unroll
            for (int nj = 0; nj < 2; nj++)
                acc[0][mi][nj] = __builtin_amdgcn_mfma_f32_16x16x32_bf16(aF[mi][0], bF0[nj][0], acc[0][mi][nj], 0, 0, 0);
        #pragma unroll
        for (int mi = 0; mi < 4; mi++)
            #pragma unroll
            for (int nj = 0; nj < 2; nj++)
                acc[0][mi][nj] = __builtin_amdgcn_mfma_f32_16x16x32_bf16(aF[mi][1], bF0[nj][1], acc[0][mi][nj], 0, 0, 0);
        __builtin_amdgcn_s_setprio(0);

        // ---- P2: quadrant (0,1) — reuse aF(A0), read bF1<-B1 ----
        #pragma unroll
        for (int nj = 0; nj < 2; nj++) {
            bF1[nj][0] = *(const bf16x8*)(&Bh[sB1][bBase + nj * 1024 + koff0]);
            bF1[nj][1] = *(const bf16x8*)(&Bh[sB1][bBase + nj * 1024 + koff1]);
        }
        __builtin_amdgcn_s_setprio(1);
        #pragma unroll
        for (int mi = 0; mi < 4; mi++)
            #pragma unroll
            for (int nj = 0; nj < 2; nj++)
                acc[1][mi][nj] = __builtin_amdgcn_mfma_f32_16x16x32_bf16(aF[mi][0], bF1[nj][0], acc[1][mi][nj], 0, 0, 0);
        #pragma unroll
        for (int mi = 0; mi < 4; mi++)
            #pragma unroll
            for (int nj = 0; nj < 2; nj++)
                acc[1][mi][nj] = __builtin_amdgcn_mfma_f32_16x16x32_bf16(aF[mi][1], bF1[nj][1], acc[1][mi][nj], 0, 0, 0);
        __builtin_amdgcn_s_setprio(0);

        // ---- mid barrier: A0(t),B1(t) reads complete everywhere (WAR fence) ----
        bar();

        // ---- P3: quadrant (1,1) — read aF<-A1, reuse bF1(B1); stage {A0,B1}(t+2) ----
        #pragma unroll
        for (int mi = 0; mi < 4; mi++) {
            aF[mi][0] = *(const bf16x8*)(&Ah[sA1][aBase + mi * 1024 + koff0]);
            aF[mi][1] = *(const bf16x8*)(&Ah[sA1][aBase + mi * 1024 + koff1]);
        }
        if (t + 2 < KT_G3) { STAGE_A(t + 2, 0); STAGE_B(t + 2, 1); }
        __builtin_amdgcn_s_setprio(1);
        #pragma unroll
        for (int mi = 0; mi < 4; mi++)
            #pragma unroll
            for (int nj = 0; nj < 2; nj++)
                acc[3][mi][nj] = __builtin_amdgcn_mfma_f32_16x16x32_bf16(aF[mi][0], bF1[nj][0], acc[3][mi][nj], 0, 0, 0);
        #pragma unroll
        for (int mi = 0; mi < 4; mi++)
            #pragma unroll
            for (int nj = 0; nj < 2; nj++)
                acc[3][mi][nj] = __builtin_amdgcn_mfma_f32_16x16x32_bf16(aF[mi][1], bF1[nj][1], acc[3][mi][nj], 0, 0, 0);
        __builtin_amdgcn_s_setprio(0);

        // ---- P4: quadrant (1,0) — reuse aF(A1) and bF0(B0): NO LDS reads ----
        __builtin_amdgcn_s_setprio(1);
        #pragma unroll
        for (int mi = 0; mi < 4; mi++)
            #pragma unroll
            for (int nj = 0; nj < 2; nj++)
                acc[2][mi][nj] = __builtin_amdgcn_mfma_f32_16x16x32_bf16(aF[mi][0], bF0[nj][0], acc[2][mi][nj], 0, 0, 0);
        #pragma unroll
        for (int mi = 0; mi < 4; mi++)
            #pragma unroll
            for (int nj = 0; nj < 2; nj++)
                acc[2][mi][nj] = __builtin_amdgcn_mfma_f32_16x16x32_bf16(aF[mi][1], bF0[nj][1], acc[2][mi][nj], 0, 0, 0);
        __builtin_amdgcn_s_setprio(0);
    }

    // ---- epilogue: C/D layout col=lane&15, row=(lane>>4)*4+reg (m89/m91) ----
    #pragma unroll
    for (int q = 0; q < 4; q++) {
        const int qm = q >> 1, qn = q & 1;
        #pragma unroll
        for (int mi = 0; mi < 4; mi++) {
            #pragma unroll
            for (int nj = 0; nj < 2; nj++) {
                #pragma unroll
                for (int r = 0; r < 4; r++) {
                    const int row = mR + qm * 128 + vm * 64 + mi * 16 + gHi * 4 + r;
                    if (row < NREAL) {
                        const int col = nR + qn * 128 + vn * 32 + nj * 16 + rRow;
                        const int c = col & 31, b = col >> 5;
                        const float bv = nj ? bias1 : bias0;
                        const float v = elu_f(acc[q][mi][nj][r] + bv);
                        outH[(size_t)b * KFC + row * 32 + c] = __float2bfloat16(v);
                    }
                }
            }
        }
    }
}

// ---------------------------------------------------------------------------
// Conversions / padding (convX + convA merged: one launch)
// ---------------------------------------------------------------------------
#define NBLK_X ((BATCH * NPAD + 255) / 256)
#define NBLK_A ((NPAD * NPAD + 255) / 256)

__global__ void convXA(const float* __restrict__ x, __hip_bfloat16* __restrict__ Xbf,
                       const float* __restrict__ a, __hip_bfloat16* __restrict__ Abf)
{
    if (blockIdx.x < NBLK_X) {
        const int idx = blockIdx.x * 256 + threadIdx.x;
        if (idx >= BATCH * NPAD) return;
        const int m = idx % NPAD, b = idx / NPAD;
        const float v = (m < NREAL) ? x[(size_t)b * NREAL + m] : 0.f;
        Xbf[idx] = __float2bfloat16(v);
    } else {
        const int idx = (blockIdx.x - NBLK_X) * 256 + threadIdx.x;
        if (idx >= NPAD * NPAD) return;
        const int m = idx % NPAD, n = idx / NPAD;
        const float v = (m < NREAL && n < NREAL) ? a[(size_t)n * NREAL + m] : 0.f;
        Abf[idx] = __float2bfloat16(v);
    }
}

// wf1 [25088][512] fp32 -> Wt [512][25088] bf16 (LDS tile transpose)
__global__ void convW(const float* __restrict__ wf1, __hip_bfloat16* __restrict__ Wt) {
    __shared__ float tile[32][33];
    const int k0 = blockIdx.x * 32, h0 = blockIdx.y * 32;
    const int tx = threadIdx.x, ty = threadIdx.y;  // (32,8)
    #pragma unroll
    for (int i = 0; i < 4; i++)
        tile[ty * 4 + i][tx] = wf1[(size_t)(k0 + ty * 4 + i) * HDIM + h0 + tx];
    __syncthreads();
    #pragma unroll
    for (int i = 0; i < 4; i++)
        Wt[(size_t)(h0 + ty * 4 + i) * KFC + k0 + tx] = __float2bfloat16(tile[tx][ty * 4 + i]);
}

// ---------------------------------------------------------------------------
// Layer-1 fused pointwise
// ---------------------------------------------------------------------------
__global__ void layer1_fuse(const float* __restrict__ Ypart,
                            const float* __restrict__ w1, const float* __restrict__ b1,
                            const float* __restrict__ w2,
                            __hip_bfloat16* __restrict__ Tt)
{
    __shared__ __align__(16) float sW2[C1D * C2D];
    __shared__ float sw1[C1D], sb1[C1D];
    const int tid = threadIdx.x;                 // 128 threads
    for (int i = tid; i < C1D * C2D; i += 128) sW2[i] = w2[i];
    if (tid < C1D) { sw1[tid] = w1[tid]; sb1[tid] = b1[tid]; }
    __syncthreads();

    const int m = blockIdx.x * 128 + tid;        // 0..895
    const int b = blockIdx.y;
    float y = 0.f;
    #pragma unroll
    for (int z = 0; z < KS_G1; z++)
        y += Ypart[(size_t)z * (BATCH * NPAD) + (size_t)b * NPAD + m];

    float h[C1D];
    #pragma unroll
    for (int c1 = 0; c1 < C1D; c1++) h[c1] = elu_f(y * sw1[c1] + sb1[c1]);

    float4 t4[8];
    #pragma unroll
    for (int q = 0; q < 8; q++) t4[q] = make_float4(0.f, 0.f, 0.f, 0.f);
    #pragma unroll
    for (int c1 = 0; c1 < C1D; c1++) {
        const float hv = h[c1];
        const float4* row = (const float4*)(sW2 + c1 * C2D);
        #pragma unroll
        for (int q = 0; q < 8; q++) {
            const float4 w = row[q];
            t4[q].x += hv * w.x; t4[q].y += hv * w.y;
            t4[q].z += hv * w.z; t4[q].w += hv * w.w;
        }
    }
    const float* tf = (const float*)t4;
    #pragma unroll
    for (int c = 0; c < C2D; c++)
        Tt[((size_t)(b * 32 + c)) * NPAD + m] = __float2bfloat16(tf[c]);
}

// ---------------------------------------------------------------------------
// fc1 reduce + relu + fc2 + softmax, fused.
// ---------------------------------------------------------------------------
__global__ void fc2_softmax(const float* __restrict__ part, const float* __restrict__ bf1,
                            const float* __restrict__ wf2, const float* __restrict__ bf2,
                            float* __restrict__ out)
{
    __shared__ float sW[HDIM * NCLS];
    __shared__ float sb[NCLS];
    const int tid = threadIdx.x;                 // 256
    for (int i = tid; i < HDIM * NCLS; i += 256) sW[i] = wf2[i];
    if (tid < NCLS) sb[tid] = bf2[tid];
    __syncthreads();

    const int lane = tid & 63, wave = tid >> 6;
    const int b = blockIdx.x * 4 + wave;

    float acc[NCLS];
    #pragma unroll
    for (int c = 0; c < NCLS; c++) acc[c] = 0.f;
    #pragma unroll
    for (int q = 0; q < 8; q++) {
        const int h = q * 64 + lane;
        float hv = bf1[h];
        #pragma unroll
        for (int z = 0; z < KS_FC; z++)
            hv += part[(size_t)z * (BATCH * HDIM) + (size_t)b * HDIM + h];
        hv = hv > 0.f ? hv : 0.f;
        #pragma unroll
        for (int c = 0; c < NCLS; c++) acc[c] += hv * sW[h * NCLS + c];
    }
    #pragma unroll
    for (int c = 0; c < NCLS; c++) {
        #pragma unroll
        for (int off = 32; off >= 1; off >>= 1) acc[c] += __shfl_down(acc[c], off);
    }
    if (lane == 0) {
        float mx = -1e30f;
        #pragma unroll
        for (int c = 0; c < NCLS; c++) { acc[c] += sb[c]; mx = fmaxf(mx, acc[c]); }
        float e[NCLS], s = 0.f;
        #pragma unroll
        for (int c = 0; c < NCLS; c++) { e[c] = __expf(acc[c] - mx); s += e[c]; }
        const float inv = 1.f / s;
        #pragma unroll
        for (int c = 0; c < NCLS; c++) out[(size_t)b * NCLS + c] = e[c] * inv;
    }
}

// ---------------------------------------------------------------------------
// Workspace layout (peak ~113.5 MB) — unchanged
//   h2f   [0,          51380224)  bf16 1024x25088  (written G3, read G4)
//     Ypart [0, 25690112) f32 7x1024x896 — overlay, dead before G3 writes h2f
//   Tt    [51380224,  110100480)  bf16 32768x896   (dead after G3)
//     Wt   [51380224, 77070336)   bf16 512x25088 — overlay after G3
//     part [77070336, 106430464)  f32 14x1024x512 — overlay after G3
//   Abf   [110100480, 111706112)  bf16 896x896
//   Xbf   [111706112, 113541120)  bf16 1024x896    (dead after G1)
// ---------------------------------------------------------------------------
extern "C" void kernel_launch(void* const* d_in, const int* in_sizes, int n_in,
                              void* d_out, int out_size, void* d_ws, size_t ws_size,
                              hipStream_t stream)
{
    const float* x   = (const float*)d_in[0];
    const float* a   = (const float*)d_in[1];
    const float* w1  = (const float*)d_in[2];
    const float* b1  = (const float*)d_in[3];
    const float* w2  = (const float*)d_in[4];
    const float* b2  = (const float*)d_in[5];
    const float* wf1 = (const float*)d_in[6];
    const float* bf1 = (const float*)d_in[7];
    const float* wf2 = (const float*)d_in[8];
    const float* bf2 = (const float*)d_in[9];
    float* out = (float*)d_out;

    char* ws = (char*)d_ws;
    __hip_bfloat16* h2f  = (__hip_bfloat16*)(ws + 0);
    float*          Ypart= (float*)(ws + 0);                  // overlay (pre-G3)
    __hip_bfloat16* Tt   = (__hip_bfloat16*)(ws + 51380224);
    __hip_bfloat16* Wt   = (__hip_bfloat16*)(ws + 51380224);  // overlay (post-G3)
    float*          part = (float*)(ws + 77070336);           // overlay (post-G3)
    __hip_bfloat16* Abf  = (__hip_bfloat16*)(ws + 110100480);
    __hip_bfloat16* Xbf  = (__hip_bfloat16*)(ws + 111706112);

    // fused input conversions (one launch)
    convXA<<<NBLK_X + NBLK_A, 256, 0, stream>>>(x, Xbf, a, Abf);

    // G1: Ypart[z][b][n] partials of sum_m Xbf[b][m]*Abf[n][m]
    //     (ring kernel: kPerZ=128 -> 2 tiles of 64; 392 blocks)
    gemm128_rg<<<dim3(NPAD / 128, BATCH / 128, KS_G1), 256, 0, stream>>>(
        Xbf, NPAD, Abf, NPAD, (NPAD / KS_G1) / 64, NPAD / KS_G1,
        (size_t)BATCH * NPAD, Ypart, NPAD);

    // layer-1 pointwise + @W2, transposed store
    layer1_fuse<<<dim3(NPAD / 128, BATCH), 128, 0, stream>>>(Ypart, w1, b1, w2, Tt);

    // G3: h2 = elu(A @ T + b2) — quadrant-phase ring 256^2 kernel (R4 + bF0 cache)
    gemm256_g3<<<dim3(BATCH * 32 / 256, 1024 / 256), 512, 0, stream>>>(Abf, Tt, h2f, b2);

    // transpose wf1 -> bf16 (into the now-dead Tt region)
    convW<<<dim3(KFC / 32, HDIM / 32), dim3(32, 8), 0, stream>>>(wf1, Wt);

    // G4: fc1 partials, split-K=14 (ring kernel: kPerZ=1792 -> 28 tiles; 448 blocks)
    gemm128_rg<<<dim3(HDIM / 128, BATCH / 128, KS_FC), 256, 0, stream>>>(
        h2f, KFC, Wt, KFC, (KFC / KS_FC) / 64, KFC / KS_FC,
        (size_t)BATCH * HDIM, part, HDIM);

    // fc1 reduce + relu + fc2 + softmax
    fc2_softmax<<<BATCH / 4, 256, 0, stream>>>(part, bf1, wf2, bf2, out);
}